// Round 7
// baseline (233.191 us; speedup 1.0000x reference)
//
#include <hip/hip_runtime.h>

// SGConv: out = A_norm^2 (x @ W^T) + b, A_norm = D^-1/2 (A+I) D^-1/2.
// yhat = dinv (.) h stored bf16; hop: h'_d = dinv_d * (sum yhat_src + yhat_d).
// R17 (resubmit — round 6 was a container failure, kernel never measured):
// xw rebuilt. Old xw: 43.5us, 4.2M LDS bank conflicts (8-way on the
// transpose stores), 19% occupancy (50KB LDS), LDS-issue-bound (48B/lane per
// 32 FMA). New xw: W lives in registers (lane=(o16,kq) holds 32 floats of
// row o=16w+o16), x stays ROW-MAJOR in LDS read by 16-lane BROADCAST;
// 144-float row stride makes the 4 kq-groups bank-disjoint (zero conflicts
// by construction); kq-reduce via 2 shfl_xor. 36KB LDS -> 4 blocks/CU.
// prop (R16, 2 nodes/wave) and p1/p2ab (R2 counting sort) unchanged.

#define FIN 128
#define FOUT 64

#define NBUK 392          // buckets of 256 nodes (node >> 8)
#define BSH  8
#define NGRP 8
#define NSEG (NBUK * NGRP)
#define CAP  1024         // per-(bucket,group) staging capacity (mean 510, +22σ)
#define SEGSH 10
#define EPB_MAX 3328
#define CAP2 4864         // per-bucket col capacity (mean 4096, +12σ)

typedef unsigned short ushort_t;
typedef unsigned int uint_t;

__device__ __forceinline__ ushort_t f2bf(float f) {           // RNE
    uint_t u = __float_as_uint(f);
    return (ushort_t)((u + 0x7fffu + ((u >> 16) & 1u)) >> 16);
}
__device__ __forceinline__ float bf2f(ushort_t v) {
    return __uint_as_float(((uint_t)v) << 16);
}

// ---- p1: block-local counting sort into (bucket, grp) segments ------------

__global__ __launch_bounds__(512) void p1_sort_kernel(const int* __restrict__ ei,
                                                      int* __restrict__ bcur,
                                                      int* __restrict__ bbuf,
                                                      int e, int epb) {
    __shared__ int entryA[EPB_MAX];
    __shared__ int sortedC[EPB_MAX];
    __shared__ ushort_t bktA[EPB_MAX];
    __shared__ ushort_t bktS[EPB_MAX];
    __shared__ int hist[512];
    __shared__ int stmp[512];
    __shared__ int loff[512];
    __shared__ int cur[512];
    __shared__ int gbase[512];

    const int tid = threadIdx.x;
    const int grp = blockIdx.x & (NGRP - 1);
    const int base = blockIdx.x * epb;
    int m = e - base; if (m > epb) m = epb; if (m < 0) m = 0;

    hist[tid] = 0; cur[tid] = 0;
    __syncthreads();

    for (int i = tid; i < m; i += 512) {
        int s = ei[base + i];
        int d = ei[e + base + i];
        int b = d >> BSH;
        entryA[i] = ((d & 255) << 17) | s;    // src < 2^17
        bktA[i]   = (ushort_t)b;
        atomicAdd(&hist[b], 1);
    }
    __syncthreads();

    int v = hist[tid];
    stmp[tid] = v;
    __syncthreads();
    for (int off = 1; off < 512; off <<= 1) {
        int add = (tid >= off) ? stmp[tid - off] : 0;
        __syncthreads();
        stmp[tid] += add;
        __syncthreads();
    }
    loff[tid] = stmp[tid] - v;
    if (tid < NBUK && v > 0) gbase[tid] = atomicAdd(&bcur[(tid << 3) | grp], v);
    __syncthreads();

    for (int i = tid; i < m; i += 512) {
        int b = bktA[i];
        int r = atomicAdd(&cur[b], 1);
        int p = loff[b] + r;
        sortedC[p] = entryA[i];
        bktS[p]    = (ushort_t)b;
    }
    __syncthreads();

    for (int i = tid; i < m; i += 512) {
        int b   = bktS[i];
        int idx = gbase[b] + (i - loff[b]);
        if (idx < CAP)
            bbuf[(((b << 3) | grp) << SEGSH) + idx] = sortedC[i];
    }
}

// ---- p2ab: one block per bucket (256 nodes) -------------------------------

__global__ __launch_bounds__(512) void p2ab_kernel(const int* __restrict__ bcur,
                                                   const int* __restrict__ bbuf,
                                                   int2* __restrict__ rowcnt,
                                                   float* __restrict__ dinv,
                                                   int* __restrict__ col, int n) {
    __shared__ int ebuf[CAP2];     // 19 KB staged entries
    __shared__ int tile[CAP2];     // 19 KB placed srcs
    __shared__ int lc[256];
    __shared__ int scn[256];
    __shared__ int lcur[256];
    __shared__ int segoff[NGRP + 1];

    const int b = blockIdx.x, tid = threadIdx.x;
    if (tid < 256) lc[tid] = 0;
    if (tid == 0) {
        int acc = 0;
        for (int g = 0; g < NGRP; ++g) {
            segoff[g] = acc;
            int mc = bcur[(b << 3) | g]; if (mc > CAP) mc = CAP;
            acc += mc;
        }
        segoff[NGRP] = acc;
    }
    __syncthreads();
    int me = segoff[NGRP]; if (me > CAP2) me = CAP2;

    for (int g = 0; g < NGRP; ++g) {
        int s0 = segoff[g], sz = segoff[g + 1] - s0;
        const int* p = bbuf + ((size_t)((b << 3) | g) << SEGSH);
        for (int i = tid; i < sz; i += 512)
            if (s0 + i < CAP2) ebuf[s0 + i] = p[i];
    }
    __syncthreads();

    for (int i = tid; i < me; i += 512)
        atomicAdd(&lc[(ebuf[i] >> 17) & 255], 1);
    __syncthreads();

    int v = 0, excl = 0;
    if (tid < 256) {
        v = lc[tid];
        scn[tid] = v;
    }
    __syncthreads();
    for (int off = 1; off < 256; off <<= 1) {
        int add = 0;
        if (tid < 256 && tid >= off) add = scn[tid - off];
        __syncthreads();
        if (tid < 256) scn[tid] += add;
        __syncthreads();
    }
    if (tid < 256) {
        excl = scn[tid] - v;
        int node = (b << BSH) + tid;
        if (node < n) {
            int2 rc; rc.x = b * CAP2 + excl; rc.y = v;
            rowcnt[node] = rc;
            dinv[node]   = rsqrtf((float)(v + 1));
        }
        lcur[tid] = excl;
    }
    __syncthreads();

    for (int i = tid; i < me; i += 512) {
        int ent = ebuf[i];
        int dl  = (ent >> 17) & 255;
        int pos = atomicAdd(&lcur[dl], 1);
        if (pos < CAP2) tile[pos] = ent & 0x1FFFF;
    }
    __syncthreads();

    int used = scn[255]; if (used > CAP2) used = CAP2;
    for (int i = tid; i < used; i += 512)
        col[b * CAP2 + i] = tile[i];
}

// ---- y0hat = dinv (.) (x @ W^T) : W-in-registers, x broadcast from LDS ----
// Block = 256 thr (4 waves), 64 nodes. lane = (o16, kq): output o = 16*wave
// + o16, k-chunk kq*32..+32 held in 8 float4 regs. x row-major in LDS with
// 144-float row stride: float4 read bank = (16*node + 4*kq + 4*j) mod 32
// -> the 4 kq address-groups are bank-disjoint, 16-lane broadcast each:
// ZERO conflicts. Per node/lane: 8 ds_read_b128 + 32 FMA; kq-reduce via
// shfl_xor(16,32); kq==0 lanes store bf16.

#define XW_NPB 64
#define XW_RS4 36          // row stride in float4s (144 floats)

__global__ __launch_bounds__(256) void xw_kernel(const float* __restrict__ x,
                                                 const float* __restrict__ W,
                                                 const float* __restrict__ dinv,
                                                 ushort_t* __restrict__ y, int n) {
    __shared__ float4 xs[XW_NPB * XW_RS4];   // 36 KB

    const int tid   = threadIdx.x;
    const int node0 = blockIdx.x * XW_NPB;

    // stage x: row-major, chunk kq at float4 slot node*36 + kq*9 + j
    {
        int k4 = tid & 31;            // float4 index within row (0..31)
        int nd = tid >> 5;            // row 0..7
        int slot = (k4 >> 3) * 9 + (k4 & 7);
#pragma unroll
        for (int it = 0; it < 8; ++it, nd += 8) {
            int gnode = node0 + nd; if (gnode > n - 1) gnode = n - 1;
            float4 v = *(const float4*)(x + (size_t)gnode * FIN + 4 * k4);
            xs[nd * XW_RS4 + slot] = v;
        }
    }

    const int lane = tid & 63;
    const int o    = ((tid >> 6) << 4) | (lane & 15);   // output 0..63
    const int kq   = lane >> 4;                         // k-quarter 0..3

    float4 w[8];
#pragma unroll
    for (int j = 0; j < 8; ++j)
        w[j] = *(const float4*)(W + (size_t)o * FIN + kq * 32 + 4 * j);

    __syncthreads();

    const float4* xb = xs + kq * 9;
    for (int nb = 0; nb < XW_NPB; nb += 2) {
        const float4* p0 = xb + nb * XW_RS4;
        const float4* p1 = p0 + XW_RS4;
        float a0 = 0.f, a1 = 0.f;
#pragma unroll
        for (int j = 0; j < 8; ++j) {
            float4 v0 = p0[j];
            a0 += v0.x * w[j].x + v0.y * w[j].y + v0.z * w[j].z + v0.w * w[j].w;
            float4 v1 = p1[j];
            a1 += v1.x * w[j].x + v1.y * w[j].y + v1.z * w[j].z + v1.w * w[j].w;
        }
        a0 += __shfl_xor(a0, 16); a0 += __shfl_xor(a0, 32);
        a1 += __shfl_xor(a1, 16); a1 += __shfl_xor(a1, 32);
        if (kq == 0) {
            int n0 = node0 + nb, n1 = n0 + 1;
            if (n0 < n) y[(size_t)n0 * FOUT + o] = f2bf(dinv[n0] * a0);
            if (n1 < n) y[(size_t)n1 * FOUT + o] = f2bf(dinv[n1] * a1);
        }
    }
}

// ---- one propagation hop: TWO nodes per wave ------------------------------
// lane l: features 4*(l&15)..+3 of row-group l>>4, for both nodes 2w, 2w+1.

#define ACC4(A0,A1,A2,A3,v)                              \
    A0 += __uint_as_float((v).x << 16);                  \
    A1 += __uint_as_float((v).x & 0xFFFF0000u);          \
    A2 += __uint_as_float((v).y << 16);                  \
    A3 += __uint_as_float((v).y & 0xFFFF0000u);

__global__ __launch_bounds__(512) void prop_kernel(const ushort_t* __restrict__ yin,
                            const int2* __restrict__ rowcnt, const int* __restrict__ col,
                            const float* __restrict__ dinv, const float* __restrict__ bias,
                            ushort_t* __restrict__ yout_bf, float* __restrict__ yout_f,
                            int n, int mode) {
    int wv   = __builtin_amdgcn_readfirstlane((blockIdx.x * blockDim.x + threadIdx.x) >> 6);
    int lane = threadIdx.x & 63;
    const int widA = wv << 1;
    if (widA >= n) return;
    const int widB = widA + 1;
    const bool hasB = (widB < n);
    const int grp = lane >> 4;          // row-group 0..3
    const int fl  = (lane & 15) << 2;   // feature base

    int2 rcA = rowcnt[widA];
    int2 rcB = rowcnt[hasB ? widB : widA];
    const int degA = rcA.y;
    const int degB = hasB ? rcB.y : 0;

    float aA0=0.f,aA1=0.f,aA2=0.f,aA3=0.f;
    float aB0=0.f,aB1=0.f,aB2=0.f,aB3=0.f;
    if (grp == 0) {                     // self loops, counted once
        uint2 vA = *(const uint2*)(yin + (size_t)widA * FOUT + fl);
        ACC4(aA0,aA1,aA2,aA3,vA)
        if (hasB) {
            uint2 vB = *(const uint2*)(yin + (size_t)widB * FOUT + fl);
            ACC4(aB0,aB1,aB2,aB3,vB)
        }
    }

    int mxdeg = degA > degB ? degA : degB;
    for (int base = 0; base < mxdeg; base += 64) {
        int cnA = degA - base; cnA = cnA < 0 ? 0 : (cnA > 64 ? 64 : cnA);
        int cnB = degB - base; cnB = cnB < 0 ? 0 : (cnB > 64 ? 64 : cnB);
        int colvA = 0, colvB = 0;
        if (cnA > 0) colvA = col[rcA.x + base + (lane < cnA ? lane : cnA - 1)];
        if (cnB > 0) colvB = col[rcB.x + base + (lane < cnB ? lane : cnB - 1)];
        int mx = cnA > cnB ? cnA : cnB;
        for (int j = 0; j < mx; j += 16) {
            // issue up to 8 predicated independent gathers, then accumulate
            uint2 vA[4], vB[4];
#pragma unroll
            for (int u = 0; u < 4; ++u) {
                int r  = j + 4 * u + grp;
                int sA = __shfl(colvA, r < cnA ? r : 0);
                int sB = __shfl(colvB, r < cnB ? r : 0);
                vA[u] = make_uint2(0u, 0u);
                vB[u] = make_uint2(0u, 0u);
                if (r < cnA) vA[u] = *(const uint2*)(yin + (size_t)sA * FOUT + fl);
                if (r < cnB) vB[u] = *(const uint2*)(yin + (size_t)sB * FOUT + fl);
            }
#pragma unroll
            for (int u = 0; u < 4; ++u) {
                ACC4(aA0,aA1,aA2,aA3,vA[u])
                ACC4(aB0,aB1,aB2,aB3,vB[u])
            }
        }
    }

    // reduce the 4 row-groups: lanes {l, l^16, l^32, l^48}
    aA0 += __shfl_xor(aA0, 16); aA0 += __shfl_xor(aA0, 32);
    aA1 += __shfl_xor(aA1, 16); aA1 += __shfl_xor(aA1, 32);
    aA2 += __shfl_xor(aA2, 16); aA2 += __shfl_xor(aA2, 32);
    aA3 += __shfl_xor(aA3, 16); aA3 += __shfl_xor(aA3, 32);
    aB0 += __shfl_xor(aB0, 16); aB0 += __shfl_xor(aB0, 32);
    aB1 += __shfl_xor(aB1, 16); aB1 += __shfl_xor(aB1, 32);
    aB2 += __shfl_xor(aB2, 16); aB2 += __shfl_xor(aB2, 32);
    aB3 += __shfl_xor(aB3, 16); aB3 += __shfl_xor(aB3, 32);

    if (lane < 16) {
        float diA = dinv[widA];
        if (mode == 0) {
            float sc = diA * diA;
            ushort4 o;
            o.x = f2bf(sc * aA0); o.y = f2bf(sc * aA1);
            o.z = f2bf(sc * aA2); o.w = f2bf(sc * aA3);
            *(ushort4*)(yout_bf + (size_t)widA * FOUT + fl) = o;
            if (hasB) {
                float diB = dinv[widB], sb2 = diB * diB;
                ushort4 p;
                p.x = f2bf(sb2 * aB0); p.y = f2bf(sb2 * aB1);
                p.z = f2bf(sb2 * aB2); p.w = f2bf(sb2 * aB3);
                *(ushort4*)(yout_bf + (size_t)widB * FOUT + fl) = p;
            }
        } else {
            float4 bo;
            bo.x = bias[fl]; bo.y = bias[fl + 1];
            bo.z = bias[fl + 2]; bo.w = bias[fl + 3];
            float4 o;
            o.x = diA * aA0 + bo.x; o.y = diA * aA1 + bo.y;
            o.z = diA * aA2 + bo.z; o.w = diA * aA3 + bo.w;
            *(float4*)(yout_f + (size_t)widA * FOUT + fl) = o;
            if (hasB) {
                float diB = dinv[widB];
                float4 p;
                p.x = diB * aB0 + bo.x; p.y = diB * aB1 + bo.y;
                p.z = diB * aB2 + bo.z; p.w = diB * aB3 + bo.w;
                *(float4*)(yout_f + (size_t)widB * FOUT + fl) = p;
            }
        }
    }
}

// ---- launch ---------------------------------------------------------------

extern "C" void kernel_launch(void* const* d_in, const int* in_sizes, int n_in,
                              void* d_out, int out_size, void* d_ws, size_t ws_size,
                              hipStream_t stream) {
    const float* x  = (const float*)d_in[0];
    const int*   ei = (const int*)d_in[1];
    const float* W  = (const float*)d_in[2];
    const float* b  = (const float*)d_in[3];
    float* out = (float*)d_out;

    int n = in_sizes[0] / FIN;   // 100000
    int e = in_sizes[1] / 2;     // 1600000

    int P1B = (e + 3124) / 3125;             // 512
    int epb = (e + P1B - 1) / P1B;           // 3125 <= EPB_MAX

    char* w = (char*)d_ws;
    int*   bbuf   = (int*)w;      w += (size_t)NSEG * CAP * sizeof(int);      // 12.85 MB
    int*   col    = (int*)w;      w += (size_t)NBUK * CAP2 * sizeof(int);     // 7.63 MB
    ushort_t* y0b = (ushort_t*)w; w += (size_t)n * FOUT * sizeof(ushort_t);   // 12.8 MB
    ushort_t* y1b = (ushort_t*)w; w += (size_t)n * FOUT * sizeof(ushort_t);   // 12.8 MB
    int2*  rowcnt = (int2*)w;     w += (size_t)n * sizeof(int2);              // 0.8 MB
    int*   bcur   = (int*)w;      w += (size_t)NSEG * sizeof(int);
    float* dinv   = (float*)w;    w += (size_t)n * sizeof(float);

    (void)hipMemsetAsync(bcur, 0, (size_t)NSEG * sizeof(int), stream);
    p1_sort_kernel<<<P1B, 512, 0, stream>>>(ei, bcur, bbuf, e, epb);
    p2ab_kernel<<<NBUK, 512, 0, stream>>>(bcur, bbuf, rowcnt, dinv, col, n);

    xw_kernel<<<(n + XW_NPB - 1) / XW_NPB, 256, 0, stream>>>(x, W, dinv, y0b, n);

    int waves = (n + 1) / 2;
    int pb = (waves + 7) / 8;                // 8 waves per 512-thread block
    prop_kernel<<<pb, 512, 0, stream>>>(y0b, rowcnt, col, dinv, nullptr, y1b, nullptr, n, 0);
    prop_kernel<<<pb, 512, 0, stream>>>(y1b, rowcnt, col, dinv, b, nullptr, out, n, 1);
}

// Round 8
// 229.311 us; speedup vs baseline: 1.0169x; 1.0169x over previous
//
#include <hip/hip_runtime.h>

// SGConv: out = A_norm^2 (x @ W^T) + b, A_norm = D^-1/2 (A+I) D^-1/2.
// yhat = dinv (.) h stored bf16; hop: h'_d = dinv_d * (sum yhat_src + yhat_d).
// R18: xw v3. R17 (1 out/lane) fixed conflicts but read 4 B per FMA through
// LDS (32KB/node for 512B unique, 4x cross-wave duplication) and stalled on a
// per-iteration dinv global load -> 56us. v3: FOUR outputs per lane
// (o=4*og+c, W slice 128 VGPR), one wave = all 64 outs x full K for its own
// 16-node stream (zero duplication), same conflict-free kq*9 LDS layout
// (measured 0 conflicts), dinv prefetched per wave + shfl. 128 FMA vs
// 8 broadcast b128 per node -> FMA-bound; floor 10.4us, predict 15-18us.
// prop (R16 2-node/wave) and p1/p2ab (R2 counting sort) unchanged.

#define FIN 128
#define FOUT 64

#define NBUK 392          // buckets of 256 nodes (node >> 8)
#define BSH  8
#define NGRP 8
#define NSEG (NBUK * NGRP)
#define CAP  1024         // per-(bucket,group) staging capacity (mean 510, +22σ)
#define SEGSH 10
#define EPB_MAX 3328
#define CAP2 4864         // per-bucket col capacity (mean 4096, +12σ)

typedef unsigned short ushort_t;
typedef unsigned int uint_t;

__device__ __forceinline__ ushort_t f2bf(float f) {           // RNE
    uint_t u = __float_as_uint(f);
    return (ushort_t)((u + 0x7fffu + ((u >> 16) & 1u)) >> 16);
}

// ---- p1: block-local counting sort into (bucket, grp) segments ------------

__global__ __launch_bounds__(512) void p1_sort_kernel(const int* __restrict__ ei,
                                                      int* __restrict__ bcur,
                                                      int* __restrict__ bbuf,
                                                      int e, int epb) {
    __shared__ int entryA[EPB_MAX];
    __shared__ int sortedC[EPB_MAX];
    __shared__ ushort_t bktA[EPB_MAX];
    __shared__ ushort_t bktS[EPB_MAX];
    __shared__ int hist[512];
    __shared__ int stmp[512];
    __shared__ int loff[512];
    __shared__ int cur[512];
    __shared__ int gbase[512];

    const int tid = threadIdx.x;
    const int grp = blockIdx.x & (NGRP - 1);
    const int base = blockIdx.x * epb;
    int m = e - base; if (m > epb) m = epb; if (m < 0) m = 0;

    hist[tid] = 0; cur[tid] = 0;
    __syncthreads();

    for (int i = tid; i < m; i += 512) {
        int s = ei[base + i];
        int d = ei[e + base + i];
        int b = d >> BSH;
        entryA[i] = ((d & 255) << 17) | s;    // src < 2^17
        bktA[i]   = (ushort_t)b;
        atomicAdd(&hist[b], 1);
    }
    __syncthreads();

    int v = hist[tid];
    stmp[tid] = v;
    __syncthreads();
    for (int off = 1; off < 512; off <<= 1) {
        int add = (tid >= off) ? stmp[tid - off] : 0;
        __syncthreads();
        stmp[tid] += add;
        __syncthreads();
    }
    loff[tid] = stmp[tid] - v;
    if (tid < NBUK && v > 0) gbase[tid] = atomicAdd(&bcur[(tid << 3) | grp], v);
    __syncthreads();

    for (int i = tid; i < m; i += 512) {
        int b = bktA[i];
        int r = atomicAdd(&cur[b], 1);
        int p = loff[b] + r;
        sortedC[p] = entryA[i];
        bktS[p]    = (ushort_t)b;
    }
    __syncthreads();

    for (int i = tid; i < m; i += 512) {
        int b   = bktS[i];
        int idx = gbase[b] + (i - loff[b]);
        if (idx < CAP)
            bbuf[(((b << 3) | grp) << SEGSH) + idx] = sortedC[i];
    }
}

// ---- p2ab: one block per bucket (256 nodes) -------------------------------

__global__ __launch_bounds__(512) void p2ab_kernel(const int* __restrict__ bcur,
                                                   const int* __restrict__ bbuf,
                                                   int2* __restrict__ rowcnt,
                                                   float* __restrict__ dinv,
                                                   int* __restrict__ col, int n) {
    __shared__ int ebuf[CAP2];     // 19 KB staged entries
    __shared__ int tile[CAP2];     // 19 KB placed srcs
    __shared__ int lc[256];
    __shared__ int scn[256];
    __shared__ int lcur[256];
    __shared__ int segoff[NGRP + 1];

    const int b = blockIdx.x, tid = threadIdx.x;
    if (tid < 256) lc[tid] = 0;
    if (tid == 0) {
        int acc = 0;
        for (int g = 0; g < NGRP; ++g) {
            segoff[g] = acc;
            int mc = bcur[(b << 3) | g]; if (mc > CAP) mc = CAP;
            acc += mc;
        }
        segoff[NGRP] = acc;
    }
    __syncthreads();
    int me = segoff[NGRP]; if (me > CAP2) me = CAP2;

    for (int g = 0; g < NGRP; ++g) {
        int s0 = segoff[g], sz = segoff[g + 1] - s0;
        const int* p = bbuf + ((size_t)((b << 3) | g) << SEGSH);
        for (int i = tid; i < sz; i += 512)
            if (s0 + i < CAP2) ebuf[s0 + i] = p[i];
    }
    __syncthreads();

    for (int i = tid; i < me; i += 512)
        atomicAdd(&lc[(ebuf[i] >> 17) & 255], 1);
    __syncthreads();

    int v = 0, excl = 0;
    if (tid < 256) {
        v = lc[tid];
        scn[tid] = v;
    }
    __syncthreads();
    for (int off = 1; off < 256; off <<= 1) {
        int add = 0;
        if (tid < 256 && tid >= off) add = scn[tid - off];
        __syncthreads();
        if (tid < 256) scn[tid] += add;
        __syncthreads();
    }
    if (tid < 256) {
        excl = scn[tid] - v;
        int node = (b << BSH) + tid;
        if (node < n) {
            int2 rc; rc.x = b * CAP2 + excl; rc.y = v;
            rowcnt[node] = rc;
            dinv[node]   = rsqrtf((float)(v + 1));
        }
        lcur[tid] = excl;
    }
    __syncthreads();

    for (int i = tid; i < me; i += 512) {
        int ent = ebuf[i];
        int dl  = (ent >> 17) & 255;
        int pos = atomicAdd(&lcur[dl], 1);
        if (pos < CAP2) tile[pos] = ent & 0x1FFFF;
    }
    __syncthreads();

    int used = scn[255]; if (used > CAP2) used = CAP2;
    for (int i = tid; i < used; i += 512)
        col[b * CAP2 + i] = tile[i];
}

// ---- y0hat = dinv (.) (x @ W^T) : 4 outs/lane, W in regs, x broadcast -----
// Block = 256 thr (4 waves), 64 nodes staged; wave wl owns nodes
// [wl*16, wl*16+16). lane = (og=lane&15, kq=lane>>4); outputs o = 4*og+c.
// W slice w[c][j] = 4x8 float4 (128 VGPR). x in LDS at conflict-free slots
// node*36 + kq*9 + j (16-lane broadcast, 4 kq groups bank-disjoint —
// measured 0 conflicts in R17). Per node: 8 b128 + 128 FMA -> FMA-bound.
// kq-reduce 2 shfl_xor per acc; dinv prefetched (lane<16) + shfl.

#define XW_NPB 64
#define XW_RS4 36          // row stride in float4s (144 floats)

__global__ __launch_bounds__(256) void xw_kernel(const float* __restrict__ x,
                                                 const float* __restrict__ W,
                                                 const float* __restrict__ dinv,
                                                 ushort_t* __restrict__ y, int n) {
    __shared__ float4 xs[XW_NPB * XW_RS4];   // 36 KB

    const int tid   = threadIdx.x;
    const int node0 = blockIdx.x * XW_NPB;

    // stage x: row-major, chunk kq at float4 slot node*36 + kq*9 + j
    {
        int k4 = tid & 31;            // float4 index within row (0..31)
        int nd = tid >> 5;            // row 0..7
        int slot = (k4 >> 3) * 9 + (k4 & 7);
#pragma unroll
        for (int it = 0; it < 8; ++it, nd += 8) {
            int gnode = node0 + nd; if (gnode > n - 1) gnode = n - 1;
            float4 v = *(const float4*)(x + (size_t)gnode * FIN + 4 * k4);
            xs[nd * XW_RS4 + slot] = v;
        }
    }

    const int wl   = tid >> 6;                 // wave 0..3
    const int lane = tid & 63;
    const int og   = lane & 15;                // out-group: outputs 4*og..+3
    const int kq   = lane >> 4;                // k-quarter 0..3

    // W slice: 4 outputs x 8 float4 of k-quarter kq
    float4 w[4][8];
#pragma unroll
    for (int c = 0; c < 4; ++c)
#pragma unroll
        for (int j = 0; j < 8; ++j)
            w[c][j] = *(const float4*)(W + (size_t)(4 * og + c) * FIN + kq * 32 + 4 * j);

    // prefetch dinv for this wave's 16 nodes (lane l<16 holds node wl*16+l)
    float dv = 0.f;
    {
        int nd = node0 + wl * 16 + (lane & 15);
        if (nd > n - 1) nd = n - 1;
        if (lane < 16) dv = dinv[nd];
    }

    __syncthreads();

    const float4* xb = xs + (wl * 16) * XW_RS4 + kq * 9;
    for (int i = 0; i < 16; ++i) {
        const float4* p = xb + i * XW_RS4;
        float a0 = 0.f, a1 = 0.f, a2 = 0.f, a3 = 0.f;
#pragma unroll
        for (int j = 0; j < 8; ++j) {
            float4 v = p[j];
            a0 += v.x * w[0][j].x + v.y * w[0][j].y + v.z * w[0][j].z + v.w * w[0][j].w;
            a1 += v.x * w[1][j].x + v.y * w[1][j].y + v.z * w[1][j].z + v.w * w[1][j].w;
            a2 += v.x * w[2][j].x + v.y * w[2][j].y + v.z * w[2][j].z + v.w * w[2][j].w;
            a3 += v.x * w[3][j].x + v.y * w[3][j].y + v.z * w[3][j].z + v.w * w[3][j].w;
        }
        a0 += __shfl_xor(a0, 16); a0 += __shfl_xor(a0, 32);
        a1 += __shfl_xor(a1, 16); a1 += __shfl_xor(a1, 32);
        a2 += __shfl_xor(a2, 16); a2 += __shfl_xor(a2, 32);
        a3 += __shfl_xor(a3, 16); a3 += __shfl_xor(a3, 32);
        float di = __shfl(dv, i);
        if (kq == 0) {
            int nd = node0 + wl * 16 + i;
            if (nd < n) {
                ushort4 o;
                o.x = f2bf(di * a0); o.y = f2bf(di * a1);
                o.z = f2bf(di * a2); o.w = f2bf(di * a3);
                *(ushort4*)(y + (size_t)nd * FOUT + 4 * og) = o;
            }
        }
    }
}

// ---- one propagation hop: TWO nodes per wave ------------------------------
// lane l: features 4*(l&15)..+3 of row-group l>>4, for both nodes 2w, 2w+1.

#define ACC4(A0,A1,A2,A3,v)                              \
    A0 += __uint_as_float((v).x << 16);                  \
    A1 += __uint_as_float((v).x & 0xFFFF0000u);          \
    A2 += __uint_as_float((v).y << 16);                  \
    A3 += __uint_as_float((v).y & 0xFFFF0000u);

__global__ __launch_bounds__(512) void prop_kernel(const ushort_t* __restrict__ yin,
                            const int2* __restrict__ rowcnt, const int* __restrict__ col,
                            const float* __restrict__ dinv, const float* __restrict__ bias,
                            ushort_t* __restrict__ yout_bf, float* __restrict__ yout_f,
                            int n, int mode) {
    int wv   = __builtin_amdgcn_readfirstlane((blockIdx.x * blockDim.x + threadIdx.x) >> 6);
    int lane = threadIdx.x & 63;
    const int widA = wv << 1;
    if (widA >= n) return;
    const int widB = widA + 1;
    const bool hasB = (widB < n);
    const int grp = lane >> 4;          // row-group 0..3
    const int fl  = (lane & 15) << 2;   // feature base

    int2 rcA = rowcnt[widA];
    int2 rcB = rowcnt[hasB ? widB : widA];
    const int degA = rcA.y;
    const int degB = hasB ? rcB.y : 0;

    float aA0=0.f,aA1=0.f,aA2=0.f,aA3=0.f;
    float aB0=0.f,aB1=0.f,aB2=0.f,aB3=0.f;
    if (grp == 0) {                     // self loops, counted once
        uint2 vA = *(const uint2*)(yin + (size_t)widA * FOUT + fl);
        ACC4(aA0,aA1,aA2,aA3,vA)
        if (hasB) {
            uint2 vB = *(const uint2*)(yin + (size_t)widB * FOUT + fl);
            ACC4(aB0,aB1,aB2,aB3,vB)
        }
    }

    int mxdeg = degA > degB ? degA : degB;
    for (int base = 0; base < mxdeg; base += 64) {
        int cnA = degA - base; cnA = cnA < 0 ? 0 : (cnA > 64 ? 64 : cnA);
        int cnB = degB - base; cnB = cnB < 0 ? 0 : (cnB > 64 ? 64 : cnB);
        int colvA = 0, colvB = 0;
        if (cnA > 0) colvA = col[rcA.x + base + (lane < cnA ? lane : cnA - 1)];
        if (cnB > 0) colvB = col[rcB.x + base + (lane < cnB ? lane : cnB - 1)];
        int mx = cnA > cnB ? cnA : cnB;
        for (int j = 0; j < mx; j += 16) {
            // issue up to 8 predicated independent gathers, then accumulate
            uint2 vA[4], vB[4];
#pragma unroll
            for (int u = 0; u < 4; ++u) {
                int r  = j + 4 * u + grp;
                int sA = __shfl(colvA, r < cnA ? r : 0);
                int sB = __shfl(colvB, r < cnB ? r : 0);
                vA[u] = make_uint2(0u, 0u);
                vB[u] = make_uint2(0u, 0u);
                if (r < cnA) vA[u] = *(const uint2*)(yin + (size_t)sA * FOUT + fl);
                if (r < cnB) vB[u] = *(const uint2*)(yin + (size_t)sB * FOUT + fl);
            }
#pragma unroll
            for (int u = 0; u < 4; ++u) {
                ACC4(aA0,aA1,aA2,aA3,vA[u])
                ACC4(aB0,aB1,aB2,aB3,vB[u])
            }
        }
    }

    // reduce the 4 row-groups: lanes {l, l^16, l^32, l^48}
    aA0 += __shfl_xor(aA0, 16); aA0 += __shfl_xor(aA0, 32);
    aA1 += __shfl_xor(aA1, 16); aA1 += __shfl_xor(aA1, 32);
    aA2 += __shfl_xor(aA2, 16); aA2 += __shfl_xor(aA2, 32);
    aA3 += __shfl_xor(aA3, 16); aA3 += __shfl_xor(aA3, 32);
    aB0 += __shfl_xor(aB0, 16); aB0 += __shfl_xor(aB0, 32);
    aB1 += __shfl_xor(aB1, 16); aB1 += __shfl_xor(aB1, 32);
    aB2 += __shfl_xor(aB2, 16); aB2 += __shfl_xor(aB2, 32);
    aB3 += __shfl_xor(aB3, 16); aB3 += __shfl_xor(aB3, 32);

    if (lane < 16) {
        float diA = dinv[widA];
        if (mode == 0) {
            float sc = diA * diA;
            ushort4 o;
            o.x = f2bf(sc * aA0); o.y = f2bf(sc * aA1);
            o.z = f2bf(sc * aA2); o.w = f2bf(sc * aA3);
            *(ushort4*)(yout_bf + (size_t)widA * FOUT + fl) = o;
            if (hasB) {
                float diB = dinv[widB], sb2 = diB * diB;
                ushort4 p;
                p.x = f2bf(sb2 * aB0); p.y = f2bf(sb2 * aB1);
                p.z = f2bf(sb2 * aB2); p.w = f2bf(sb2 * aB3);
                *(ushort4*)(yout_bf + (size_t)widB * FOUT + fl) = p;
            }
        } else {
            float4 bo;
            bo.x = bias[fl]; bo.y = bias[fl + 1];
            bo.z = bias[fl + 2]; bo.w = bias[fl + 3];
            float4 o;
            o.x = diA * aA0 + bo.x; o.y = diA * aA1 + bo.y;
            o.z = diA * aA2 + bo.z; o.w = diA * aA3 + bo.w;
            *(float4*)(yout_f + (size_t)widA * FOUT + fl) = o;
            if (hasB) {
                float diB = dinv[widB];
                float4 p;
                p.x = diB * aB0 + bo.x; p.y = diB * aB1 + bo.y;
                p.z = diB * aB2 + bo.z; p.w = diB * aB3 + bo.w;
                *(float4*)(yout_f + (size_t)widB * FOUT + fl) = p;
            }
        }
    }
}

// ---- launch ---------------------------------------------------------------

extern "C" void kernel_launch(void* const* d_in, const int* in_sizes, int n_in,
                              void* d_out, int out_size, void* d_ws, size_t ws_size,
                              hipStream_t stream) {
    const float* x  = (const float*)d_in[0];
    const int*   ei = (const int*)d_in[1];
    const float* W  = (const float*)d_in[2];
    const float* b  = (const float*)d_in[3];
    float* out = (float*)d_out;

    int n = in_sizes[0] / FIN;   // 100000
    int e = in_sizes[1] / 2;     // 1600000

    int P1B = (e + 3124) / 3125;             // 512
    int epb = (e + P1B - 1) / P1B;           // 3125 <= EPB_MAX

    char* w = (char*)d_ws;
    int*   bbuf   = (int*)w;      w += (size_t)NSEG * CAP * sizeof(int);      // 12.85 MB
    int*   col    = (int*)w;      w += (size_t)NBUK * CAP2 * sizeof(int);     // 7.63 MB
    ushort_t* y0b = (ushort_t*)w; w += (size_t)n * FOUT * sizeof(ushort_t);   // 12.8 MB
    ushort_t* y1b = (ushort_t*)w; w += (size_t)n * FOUT * sizeof(ushort_t);   // 12.8 MB
    int2*  rowcnt = (int2*)w;     w += (size_t)n * sizeof(int2);              // 0.8 MB
    int*   bcur   = (int*)w;      w += (size_t)NSEG * sizeof(int);
    float* dinv   = (float*)w;    w += (size_t)n * sizeof(float);

    (void)hipMemsetAsync(bcur, 0, (size_t)NSEG * sizeof(int), stream);
    p1_sort_kernel<<<P1B, 512, 0, stream>>>(ei, bcur, bbuf, e, epb);
    p2ab_kernel<<<NBUK, 512, 0, stream>>>(bcur, bbuf, rowcnt, dinv, col, n);

    xw_kernel<<<(n + XW_NPB - 1) / XW_NPB, 256, 0, stream>>>(x, W, dinv, y0b, n);

    int waves = (n + 1) / 2;
    int pb = (waves + 7) / 8;                // 8 waves per 512-thread block
    prop_kernel<<<pb, 512, 0, stream>>>(y0b, rowcnt, col, dinv, nullptr, y1b, nullptr, n, 0);
    prop_kernel<<<pb, 512, 0, stream>>>(y1b, rowcnt, col, dinv, b, nullptr, out, n, 1);
}

// Round 9
// 214.914 us; speedup vs baseline: 1.0850x; 1.0670x over previous
//
#include <hip/hip_runtime.h>

// SGConv: out = A_norm^2 (x @ W^T) + b, A_norm = D^-1/2 (A+I) D^-1/2.
// yhat = dinv (.) h stored bf16; hop: h'_d = dinv_d * (sum yhat_src + yhat_d).
// R19: xw = ORIGINAL blocked SGEMM (measured 43.5us) with its two measured
// defects fixed in place: (1) 8-way bank conflicts on transpose stores ->
// XOR group swizzle (x at k*128 + (((nd>>3)^(k>>2))<<3|(nd&7)), writes 2-way
// = free, reads broadcast conflict-free, b128 alignment kept); (2) occupancy
// 19% (50KB LDS) -> K split into 4 panels of 32: LDS 24.7KB -> 6 blocks/CU.
// R17/R18 rewrites both lost to the original (56/53 vs 43.5): R18's W-in-reg
// plan needed 128 VGPR, compiler allocated 84 and re-loaded W per iteration.
// prop (R16 2-node/wave) and p1/p2ab (R2 counting sort) unchanged.

#define FIN 128
#define FOUT 64
#define BN 128
#define KC2 32

#define NBUK 392          // buckets of 256 nodes (node >> 8)
#define BSH  8
#define NGRP 8
#define NSEG (NBUK * NGRP)
#define CAP  1024         // per-(bucket,group) staging capacity (mean 510, +22σ)
#define SEGSH 10
#define EPB_MAX 3328
#define CAP2 4864         // per-bucket col capacity (mean 4096, +12σ)

typedef unsigned short ushort_t;
typedef unsigned int uint_t;

__device__ __forceinline__ ushort_t f2bf(float f) {           // RNE
    uint_t u = __float_as_uint(f);
    return (ushort_t)((u + 0x7fffu + ((u >> 16) & 1u)) >> 16);
}

// ---- p1: block-local counting sort into (bucket, grp) segments ------------

__global__ __launch_bounds__(512) void p1_sort_kernel(const int* __restrict__ ei,
                                                      int* __restrict__ bcur,
                                                      int* __restrict__ bbuf,
                                                      int e, int epb) {
    __shared__ int entryA[EPB_MAX];
    __shared__ int sortedC[EPB_MAX];
    __shared__ ushort_t bktA[EPB_MAX];
    __shared__ ushort_t bktS[EPB_MAX];
    __shared__ int hist[512];
    __shared__ int stmp[512];
    __shared__ int loff[512];
    __shared__ int cur[512];
    __shared__ int gbase[512];

    const int tid = threadIdx.x;
    const int grp = blockIdx.x & (NGRP - 1);
    const int base = blockIdx.x * epb;
    int m = e - base; if (m > epb) m = epb; if (m < 0) m = 0;

    hist[tid] = 0; cur[tid] = 0;
    __syncthreads();

    for (int i = tid; i < m; i += 512) {
        int s = ei[base + i];
        int d = ei[e + base + i];
        int b = d >> BSH;
        entryA[i] = ((d & 255) << 17) | s;    // src < 2^17
        bktA[i]   = (ushort_t)b;
        atomicAdd(&hist[b], 1);
    }
    __syncthreads();

    int v = hist[tid];
    stmp[tid] = v;
    __syncthreads();
    for (int off = 1; off < 512; off <<= 1) {
        int add = (tid >= off) ? stmp[tid - off] : 0;
        __syncthreads();
        stmp[tid] += add;
        __syncthreads();
    }
    loff[tid] = stmp[tid] - v;
    if (tid < NBUK && v > 0) gbase[tid] = atomicAdd(&bcur[(tid << 3) | grp], v);
    __syncthreads();

    for (int i = tid; i < m; i += 512) {
        int b = bktA[i];
        int r = atomicAdd(&cur[b], 1);
        int p = loff[b] + r;
        sortedC[p] = entryA[i];
        bktS[p]    = (ushort_t)b;
    }
    __syncthreads();

    for (int i = tid; i < m; i += 512) {
        int b   = bktS[i];
        int idx = gbase[b] + (i - loff[b]);
        if (idx < CAP)
            bbuf[(((b << 3) | grp) << SEGSH) + idx] = sortedC[i];
    }
}

// ---- p2ab: one block per bucket (256 nodes) -------------------------------

__global__ __launch_bounds__(512) void p2ab_kernel(const int* __restrict__ bcur,
                                                   const int* __restrict__ bbuf,
                                                   int2* __restrict__ rowcnt,
                                                   float* __restrict__ dinv,
                                                   int* __restrict__ col, int n) {
    __shared__ int ebuf[CAP2];     // 19 KB staged entries
    __shared__ int tile[CAP2];     // 19 KB placed srcs
    __shared__ int lc[256];
    __shared__ int scn[256];
    __shared__ int lcur[256];
    __shared__ int segoff[NGRP + 1];

    const int b = blockIdx.x, tid = threadIdx.x;
    if (tid < 256) lc[tid] = 0;
    if (tid == 0) {
        int acc = 0;
        for (int g = 0; g < NGRP; ++g) {
            segoff[g] = acc;
            int mc = bcur[(b << 3) | g]; if (mc > CAP) mc = CAP;
            acc += mc;
        }
        segoff[NGRP] = acc;
    }
    __syncthreads();
    int me = segoff[NGRP]; if (me > CAP2) me = CAP2;

    for (int g = 0; g < NGRP; ++g) {
        int s0 = segoff[g], sz = segoff[g + 1] - s0;
        const int* p = bbuf + ((size_t)((b << 3) | g) << SEGSH);
        for (int i = tid; i < sz; i += 512)
            if (s0 + i < CAP2) ebuf[s0 + i] = p[i];
    }
    __syncthreads();

    for (int i = tid; i < me; i += 512)
        atomicAdd(&lc[(ebuf[i] >> 17) & 255], 1);
    __syncthreads();

    int v = 0, excl = 0;
    if (tid < 256) {
        v = lc[tid];
        scn[tid] = v;
    }
    __syncthreads();
    for (int off = 1; off < 256; off <<= 1) {
        int add = 0;
        if (tid < 256 && tid >= off) add = scn[tid - off];
        __syncthreads();
        if (tid < 256) scn[tid] += add;
        __syncthreads();
    }
    if (tid < 256) {
        excl = scn[tid] - v;
        int node = (b << BSH) + tid;
        if (node < n) {
            int2 rc; rc.x = b * CAP2 + excl; rc.y = v;
            rowcnt[node] = rc;
            dinv[node]   = rsqrtf((float)(v + 1));
        }
        lcur[tid] = excl;
    }
    __syncthreads();

    for (int i = tid; i < me; i += 512) {
        int ent = ebuf[i];
        int dl  = (ent >> 17) & 255;
        int pos = atomicAdd(&lcur[dl], 1);
        if (pos < CAP2) tile[pos] = ent & 0x1FFFF;
    }
    __syncthreads();

    int used = scn[255]; if (used > CAP2) used = CAP2;
    for (int i = tid; i < used; i += 512)
        col[b * CAP2 + i] = tile[i];
}

// ---- y0hat = dinv (.) (x @ W^T) : blocked SGEMM, swizzled LDS, 4 K-panels -
// Block 256 thr, 128 nodes. Thread (n8=tid>>4, o4=tid&15) owns nodes
// 8*n8..+7 x outs 4*o4..+3 (acc[8] float4). Per panel p (K=32): stage x
// transposed with XOR group swizzle (write banks 2-way = free), W with
// o-fast mapping (2-way); inner loop k=0..31: 2 x-b128 broadcasts + 1
// W-b128 per 32 FMA. LDS 24.7 KB -> 6 blocks/CU.

__global__ __launch_bounds__(256) void xw_kernel(const float* __restrict__ x,
                                                 const float* __restrict__ W,
                                                 const float* __restrict__ dinv,
                                                 ushort_t* __restrict__ y, int n) {
    __shared__ float xsf[KC2 * BN];     // 16 KB
    __shared__ float wsf[KC2 * 68];     // 8.7 KB

    const int tid   = threadIdx.x;
    const int node0 = blockIdx.x * BN;
    const int n8 = tid >> 4;
    const int o4 = tid & 15;

    float4 acc[8];
#pragma unroll
    for (int i = 0; i < 8; ++i) acc[i] = make_float4(0.f, 0.f, 0.f, 0.f);

    for (int p = 0; p < FIN / KC2; ++p) {     // 4 panels of K=32
        __syncthreads();
        // stage x transposed: thread k4=tid&7 (float4 col), nd=tid>>3 (+32*it)
        {
            int k4 = tid & 7;
            int nd = tid >> 3;
#pragma unroll
            for (int it = 0; it < 4; ++it, nd += 32) {
                int gn = node0 + nd; if (gn > n - 1) gn = n - 1;
                float4 v = *(const float4*)(x + (size_t)gn * FIN + p * KC2 + 4 * k4);
                int bas = ((((nd >> 3) ^ k4) & 15) << 3) | (nd & 7);   // swizzle
                xsf[(4 * k4 + 0) * BN + bas] = v.x;
                xsf[(4 * k4 + 1) * BN + bas] = v.y;
                xsf[(4 * k4 + 2) * BN + bas] = v.z;
                xsf[(4 * k4 + 3) * BN + bas] = v.w;
            }
        }
        // stage W: o = tid&63 lane-fast (2-way banks), k4w = (tid>>6) + 4*it
        {
            int o  = tid & 63;
            int ks = tid >> 6;
#pragma unroll
            for (int it = 0; it < 2; ++it) {
                int k4w = ks + 4 * it;
                float4 v = *(const float4*)(W + (size_t)o * FIN + p * KC2 + 4 * k4w);
                wsf[(4 * k4w + 0) * 68 + o] = v.x;
                wsf[(4 * k4w + 1) * 68 + o] = v.y;
                wsf[(4 * k4w + 2) * 68 + o] = v.z;
                wsf[(4 * k4w + 3) * 68 + o] = v.w;
            }
        }
        __syncthreads();
#pragma unroll 4
        for (int k = 0; k < KC2; ++k) {
            const float* xp = xsf + k * BN + (((n8 ^ (k >> 2)) & 15) << 3);
            float4 xa0 = *(const float4*)(xp);
            float4 xa1 = *(const float4*)(xp + 4);
            float4 wb  = *(const float4*)(wsf + k * 68 + 4 * o4);
            float xe[8] = {xa0.x, xa0.y, xa0.z, xa0.w, xa1.x, xa1.y, xa1.z, xa1.w};
#pragma unroll
            for (int i = 0; i < 8; ++i) {
                acc[i].x += xe[i] * wb.x;
                acc[i].y += xe[i] * wb.y;
                acc[i].z += xe[i] * wb.z;
                acc[i].w += xe[i] * wb.w;
            }
        }
    }
#pragma unroll
    for (int i = 0; i < 8; ++i) {
        int nd = node0 + 8 * n8 + i;
        if (nd < n) {
            float di = dinv[nd];
            ushort4 o;
            o.x = f2bf(di * acc[i].x); o.y = f2bf(di * acc[i].y);
            o.z = f2bf(di * acc[i].z); o.w = f2bf(di * acc[i].w);
            *(ushort4*)(y + (size_t)nd * FOUT + 4 * o4) = o;
        }
    }
}

// ---- one propagation hop: TWO nodes per wave ------------------------------
// lane l: features 4*(l&15)..+3 of row-group l>>4, for both nodes 2w, 2w+1.

#define ACC4(A0,A1,A2,A3,v)                              \
    A0 += __uint_as_float((v).x << 16);                  \
    A1 += __uint_as_float((v).x & 0xFFFF0000u);          \
    A2 += __uint_as_float((v).y << 16);                  \
    A3 += __uint_as_float((v).y & 0xFFFF0000u);

__global__ __launch_bounds__(512) void prop_kernel(const ushort_t* __restrict__ yin,
                            const int2* __restrict__ rowcnt, const int* __restrict__ col,
                            const float* __restrict__ dinv, const float* __restrict__ bias,
                            ushort_t* __restrict__ yout_bf, float* __restrict__ yout_f,
                            int n, int mode) {
    int wv   = __builtin_amdgcn_readfirstlane((blockIdx.x * blockDim.x + threadIdx.x) >> 6);
    int lane = threadIdx.x & 63;
    const int widA = wv << 1;
    if (widA >= n) return;
    const int widB = widA + 1;
    const bool hasB = (widB < n);
    const int grp = lane >> 4;          // row-group 0..3
    const int fl  = (lane & 15) << 2;   // feature base

    int2 rcA = rowcnt[widA];
    int2 rcB = rowcnt[hasB ? widB : widA];
    const int degA = rcA.y;
    const int degB = hasB ? rcB.y : 0;

    float aA0=0.f,aA1=0.f,aA2=0.f,aA3=0.f;
    float aB0=0.f,aB1=0.f,aB2=0.f,aB3=0.f;
    if (grp == 0) {                     // self loops, counted once
        uint2 vA = *(const uint2*)(yin + (size_t)widA * FOUT + fl);
        ACC4(aA0,aA1,aA2,aA3,vA)
        if (hasB) {
            uint2 vB = *(const uint2*)(yin + (size_t)widB * FOUT + fl);
            ACC4(aB0,aB1,aB2,aB3,vB)
        }
    }

    int mxdeg = degA > degB ? degA : degB;
    for (int base = 0; base < mxdeg; base += 64) {
        int cnA = degA - base; cnA = cnA < 0 ? 0 : (cnA > 64 ? 64 : cnA);
        int cnB = degB - base; cnB = cnB < 0 ? 0 : (cnB > 64 ? 64 : cnB);
        int colvA = 0, colvB = 0;
        if (cnA > 0) colvA = col[rcA.x + base + (lane < cnA ? lane : cnA - 1)];
        if (cnB > 0) colvB = col[rcB.x + base + (lane < cnB ? lane : cnB - 1)];
        int mx = cnA > cnB ? cnA : cnB;
        for (int j = 0; j < mx; j += 16) {
            // issue up to 8 predicated independent gathers, then accumulate
            uint2 vA[4], vB[4];
#pragma unroll
            for (int u = 0; u < 4; ++u) {
                int r  = j + 4 * u + grp;
                int sA = __shfl(colvA, r < cnA ? r : 0);
                int sB = __shfl(colvB, r < cnB ? r : 0);
                vA[u] = make_uint2(0u, 0u);
                vB[u] = make_uint2(0u, 0u);
                if (r < cnA) vA[u] = *(const uint2*)(yin + (size_t)sA * FOUT + fl);
                if (r < cnB) vB[u] = *(const uint2*)(yin + (size_t)sB * FOUT + fl);
            }
#pragma unroll
            for (int u = 0; u < 4; ++u) {
                ACC4(aA0,aA1,aA2,aA3,vA[u])
                ACC4(aB0,aB1,aB2,aB3,vB[u])
            }
        }
    }

    // reduce the 4 row-groups: lanes {l, l^16, l^32, l^48}
    aA0 += __shfl_xor(aA0, 16); aA0 += __shfl_xor(aA0, 32);
    aA1 += __shfl_xor(aA1, 16); aA1 += __shfl_xor(aA1, 32);
    aA2 += __shfl_xor(aA2, 16); aA2 += __shfl_xor(aA2, 32);
    aA3 += __shfl_xor(aA3, 16); aA3 += __shfl_xor(aA3, 32);
    aB0 += __shfl_xor(aB0, 16); aB0 += __shfl_xor(aB0, 32);
    aB1 += __shfl_xor(aB1, 16); aB1 += __shfl_xor(aB1, 32);
    aB2 += __shfl_xor(aB2, 16); aB2 += __shfl_xor(aB2, 32);
    aB3 += __shfl_xor(aB3, 16); aB3 += __shfl_xor(aB3, 32);

    if (lane < 16) {
        float diA = dinv[widA];
        if (mode == 0) {
            float sc = diA * diA;
            ushort4 o;
            o.x = f2bf(sc * aA0); o.y = f2bf(sc * aA1);
            o.z = f2bf(sc * aA2); o.w = f2bf(sc * aA3);
            *(ushort4*)(yout_bf + (size_t)widA * FOUT + fl) = o;
            if (hasB) {
                float diB = dinv[widB], sb2 = diB * diB;
                ushort4 p;
                p.x = f2bf(sb2 * aB0); p.y = f2bf(sb2 * aB1);
                p.z = f2bf(sb2 * aB2); p.w = f2bf(sb2 * aB3);
                *(ushort4*)(yout_bf + (size_t)widB * FOUT + fl) = p;
            }
        } else {
            float4 bo;
            bo.x = bias[fl]; bo.y = bias[fl + 1];
            bo.z = bias[fl + 2]; bo.w = bias[fl + 3];
            float4 o;
            o.x = diA * aA0 + bo.x; o.y = diA * aA1 + bo.y;
            o.z = diA * aA2 + bo.z; o.w = diA * aA3 + bo.w;
            *(float4*)(yout_f + (size_t)widA * FOUT + fl) = o;
            if (hasB) {
                float diB = dinv[widB];
                float4 p;
                p.x = diB * aB0 + bo.x; p.y = diB * aB1 + bo.y;
                p.z = diB * aB2 + bo.z; p.w = diB * aB3 + bo.w;
                *(float4*)(yout_f + (size_t)widB * FOUT + fl) = p;
            }
        }
    }
}

// ---- launch ---------------------------------------------------------------

extern "C" void kernel_launch(void* const* d_in, const int* in_sizes, int n_in,
                              void* d_out, int out_size, void* d_ws, size_t ws_size,
                              hipStream_t stream) {
    const float* x  = (const float*)d_in[0];
    const int*   ei = (const int*)d_in[1];
    const float* W  = (const float*)d_in[2];
    const float* b  = (const float*)d_in[3];
    float* out = (float*)d_out;

    int n = in_sizes[0] / FIN;   // 100000
    int e = in_sizes[1] / 2;     // 1600000

    int P1B = (e + 3124) / 3125;             // 512
    int epb = (e + P1B - 1) / P1B;           // 3125 <= EPB_MAX

    char* w = (char*)d_ws;
    int*   bbuf   = (int*)w;      w += (size_t)NSEG * CAP * sizeof(int);      // 12.85 MB
    int*   col    = (int*)w;      w += (size_t)NBUK * CAP2 * sizeof(int);     // 7.63 MB
    ushort_t* y0b = (ushort_t*)w; w += (size_t)n * FOUT * sizeof(ushort_t);   // 12.8 MB
    ushort_t* y1b = (ushort_t*)w; w += (size_t)n * FOUT * sizeof(ushort_t);   // 12.8 MB
    int2*  rowcnt = (int2*)w;     w += (size_t)n * sizeof(int2);              // 0.8 MB
    int*   bcur   = (int*)w;      w += (size_t)NSEG * sizeof(int);
    float* dinv   = (float*)w;    w += (size_t)n * sizeof(float);

    (void)hipMemsetAsync(bcur, 0, (size_t)NSEG * sizeof(int), stream);
    p1_sort_kernel<<<P1B, 512, 0, stream>>>(ei, bcur, bbuf, e, epb);
    p2ab_kernel<<<NBUK, 512, 0, stream>>>(bcur, bbuf, rowcnt, dinv, col, n);

    xw_kernel<<<(n + BN - 1) / BN, 256, 0, stream>>>(x, W, dinv, y0b, n);

    int waves = (n + 1) / 2;
    int pb = (waves + 7) / 8;                // 8 waves per 512-thread block
    prop_kernel<<<pb, 512, 0, stream>>>(y0b, rowcnt, col, dinv, nullptr, y1b, nullptr, n, 0);
    prop_kernel<<<pb, 512, 0, stream>>>(y1b, rowcnt, col, dinv, b, nullptr, out, n, 1);
}